// Round 14
// baseline (841.905 us; speedup 1.0000x reference)
//
#include <hip/hip_runtime.h>
#include <hip/hip_bf16.h>

#define NN 50000
#define EE 600000
#define AA 8
#define CC 128
#define TT 16
#define TE 4
#define LL 4
#define BB 256
#define ENC 128
#define NCLS 10
#define SROW 136   // m_bf LDS row stride in ushorts (272B)
#define S4R 528    // s4 LDS row stride in ushorts (1056B)

typedef __attribute__((ext_vector_type(8))) short bf16x8;
typedef __attribute__((ext_vector_type(4))) float fx4;

__device__ __forceinline__ float b2f(ushort u) {
    union { float f; uint32_t i; } v; v.i = ((uint32_t)u) << 16; return v.f;
}
__device__ __forceinline__ ushort f2b(float f) {
    union { float f; uint32_t i; } v; v.f = f;
    uint32_t x = v.i;
    x += 0x7FFFu + ((x >> 16) & 1u);
    return (ushort)(x >> 16);
}
__device__ __forceinline__ float ldw(const void* p, long i, int isf) {
    return isf ? ((const float*)p)[i] : b2f(((const ushort*)p)[i]);
}
__device__ __forceinline__ float sigm(float t) { return 1.f / (1.f + __expf(-t)); }

// ---------------- dtype sniff ----------------
__global__ void sniff_kernel(int* flag, const void* W_enc_raw) {
    const ushort* u = (const ushort*)W_enc_raw;
    int good = 0;
    for (int i = 0; i < 256; ++i) {
        ushort v = u[i];
        int ex = (v >> 7) & 0xFF;
        if (v == 0 || (ex >= 100 && ex <= 126)) ++good;
    }
    *flag = (good >= 230) ? 0 : 1;   // 0 = bf16, 1 = f32
}

// ---------------- W_msg -> wstk[l][d][t*128+c]  (bf16, K=512 stacked) ----------------
__global__ __launch_bounds__(256) void wstk_kernel(ushort* __restrict__ wstk,
                                                   const void* __restrict__ W,
                                                   const int* __restrict__ flag) {
    const int isf = *flag;
    int idx = blockIdx.x * 256 + threadIdx.x;     // 0 .. 262143
    int l = idx >> 16;                             // layer 0..3
    int rem = idx & 65535;
    int d = rem >> 9, r2 = rem & 511;
    int t = r2 >> 7, c = r2 & 127;
    long src = ((long)(l * 4 + t) << 14) + c * 128 + d;   // W_msg[l][t][c][d]
    wstk[idx] = isf ? f2b(((const float*)W)[src]) : ((const ushort*)W)[src];
}

// ---------------- Wih||Whh -> bf16 ----------------
__global__ __launch_bounds__(256) void wgru_kernel(ushort* __restrict__ wgb,
                                                   const void* __restrict__ Wih,
                                                   const void* __restrict__ Whh,
                                                   const int* __restrict__ flag) {
    const int isf = *flag;
    int idx = blockIdx.x * 256 + threadIdx.x;
    if (idx >= 98304) return;
    int ih = (idx < 49152);
    int off = ih ? idx : idx - 49152;
    wgb[idx] = f2b(ldw(ih ? Wih : Whh, off, isf));
}

// ---------------- W_enc -> bf16 transposed [ENC][2048] ----------------
__global__ __launch_bounds__(256) void wencT_kernel(ushort* __restrict__ wencT,
                                                    const void* __restrict__ W_enc,
                                                    const int* __restrict__ flag) {
    const int isf = *flag;
    int idx = blockIdx.x * 256 + threadIdx.x;
    int j = idx >> 11, k = idx & 2047;
    wencT[idx] = f2b(ldw(W_enc, (long)k * ENC + j, isf));
}

// ---------------- small params -> f32 scratch ----------------
// 0 bih(384) | 384 bhh(384) | 768 b_enc(128) | 896 w_attn(128)
// 1024 b_dec(10) | 1034 b_attn(1) | 1040 W_dec(1280) | total 2320
__global__ __launch_bounds__(256) void bconv_kernel(float* __restrict__ cvt,
                                                    const void* __restrict__ bih, const void* __restrict__ bhh,
                                                    const void* __restrict__ b_enc, const void* __restrict__ w_attn,
                                                    const void* __restrict__ b_dec, const void* __restrict__ b_attn,
                                                    const void* __restrict__ W_dec,
                                                    const int* __restrict__ flag) {
    const int isf = *flag;
    int i = blockIdx.x * 256 + threadIdx.x;
    if (i < 384) cvt[i] = ldw(bih, i, isf);
    else if (i < 768) cvt[i] = ldw(bhh, i - 384, isf);
    else if (i < 896) cvt[i] = ldw(b_enc, i - 768, isf);
    else if (i < 1024) cvt[i] = ldw(w_attn, i - 896, isf);
    else if (i < 1034) cvt[i] = ldw(b_dec, i - 1024, isf);
    else if (i == 1034) cvt[i] = ldw(b_attn, 0, isf);
    else if (i >= 1040 && i < 2320) cvt[i] = ldw(W_dec, i - 1040, isf);
}

// ---------------- embed: bf16 state ----------------
__global__ __launch_bounds__(256) void embed_kernel(
    ushort* __restrict__ xbf,
    const int* __restrict__ x_type, const int* __restrict__ x_attrs,
    const int* __restrict__ x_mask, const void* __restrict__ type_emb,
    const void* __restrict__ attr_emb, const int* __restrict__ flag) {
    const int isf = *flag;
    int idx = blockIdx.x * 256 + threadIdx.x;
    int n = idx >> 6, c = idx & 63;
    if (n >= NN) return;
    int ty = x_type[n];
    xbf[n * CC + c] = f2b(ldw(type_emb, ty * 64 + c, isf));
    int cnt = x_mask[n];
    float s = 0.f;
    for (int a = 0; a < cnt; ++a) s += ldw(attr_emb, x_attrs[n * AA + a] * 64 + c, isf);
    xbf[n * CC + 64 + c] = f2b(s / (float)cnt);
}

// ---------------- CSR build ----------------
__global__ __launch_bounds__(256) void deg_kernel(int* __restrict__ cnt, const int* __restrict__ ei) {
    int e = blockIdx.x * 256 + threadIdx.x;
    if (e < EE) atomicAdd(&cnt[ei[EE + e]], 1);
}
__global__ __launch_bounds__(256) void scan1_kernel(int* __restrict__ cnt, int* __restrict__ btot) {
    __shared__ int s[256];
    int tid = threadIdx.x, i = blockIdx.x * 256 + tid;
    int v = (i < NN) ? cnt[i] : 0;
    s[tid] = v; __syncthreads();
    for (int off = 1; off < 256; off <<= 1) {
        int t = (tid >= off) ? s[tid - off] : 0; __syncthreads();
        s[tid] += t; __syncthreads();
    }
    if (i < NN) cnt[i] = s[tid] - v;
    if (tid == 255) btot[blockIdx.x] = s[255];
}
__global__ __launch_bounds__(256) void scan2_kernel(int* __restrict__ btot, int nb) {
    __shared__ int s[256];
    int tid = threadIdx.x;
    int v = (tid < nb) ? btot[tid] : 0;
    s[tid] = v; __syncthreads();
    for (int off = 1; off < 256; off <<= 1) {
        int t = (tid >= off) ? s[tid - off] : 0; __syncthreads();
        s[tid] += t; __syncthreads();
    }
    if (tid < nb) btot[tid] = s[tid] - v;
}
__global__ __launch_bounds__(256) void scan3_kernel(int* __restrict__ cnt, const int* __restrict__ btot) {
    int i = blockIdx.x * 256 + threadIdx.x;
    if (i < NN) cnt[i] += btot[blockIdx.x];
}
__global__ __launch_bounds__(256) void fill_kernel(uint* __restrict__ csr, int* __restrict__ cnt,
                                                   const int* __restrict__ ei, const int* __restrict__ ea) {
    int e = blockIdx.x * 256 + threadIdx.x;
    if (e >= EE) return;
    int d = ei[EE + e];
    int pos = atomicAdd(&cnt[d], 1);
    csr[pos] = (uint)ei[e] | ((uint)ea[e] << 16);
}

// ---------------- fused layer: per-thread gather -> LDS -> msg GEMM -> GRU ----------------
// block = 16 nodes, 256 threads. grid = NN/16 = 3125 (exact).
template <int AGG>
__global__ __launch_bounds__(256) void layer_fused(
    const ushort* __restrict__ xin, ushort* __restrict__ xout,
    const ushort* __restrict__ wl, const ushort* __restrict__ wgb,
    const float* __restrict__ cvt,
    const uint* __restrict__ csr, const int* __restrict__ endp,
    float* __restrict__ sums, float* __restrict__ cnta,
    const int* __restrict__ batch, const int* __restrict__ x_type) {
    __shared__ ushort s_s4[16][S4R];   // per-node 4-type neighbor sums (bf16), 16.5 KB
    __shared__ ushort m_bf[16][SROW];  // message result, 4.3 KB
    int tid = threadIdx.x;
    int node0 = blockIdx.x * 16;

    // ---- phase 1: gather. thread = (node, 8-ch group); 16 threads/node read rows coalesced ----
    {
        int n = tid >> 4, cg = tid & 15;
        int node = node0 + n;
        int start = (node == 0) ? 0 : endp[node - 1];
        int end = endp[node];
        float a0[8] = {0,0,0,0,0,0,0,0}, a1[8] = {0,0,0,0,0,0,0,0};
        float a2[8] = {0,0,0,0,0,0,0,0}, a3[8] = {0,0,0,0,0,0,0,0};
        for (int i = start; i < end; ++i) {
            uint pk = csr[i];                      // uniform within 16-thread group
            uint src = pk & 0xFFFFu, t = pk >> 16;
            bf16x8 v = *(const bf16x8*)&xin[((size_t)src << 7) + cg * 8];
            float f[8];
#pragma unroll
            for (int j = 0; j < 8; ++j) f[j] = b2f((ushort)v[j]);
            if (t == 0) {
#pragma unroll
                for (int j = 0; j < 8; ++j) a0[j] += f[j];
            } else if (t == 1) {
#pragma unroll
                for (int j = 0; j < 8; ++j) a1[j] += f[j];
            } else if (t == 2) {
#pragma unroll
                for (int j = 0; j < 8; ++j) a2[j] += f[j];
            } else {
#pragma unroll
                for (int j = 0; j < 8; ++j) a3[j] += f[j];
            }
        }
        bf16x8 o;
#pragma unroll
        for (int j = 0; j < 8; ++j) o[j] = (short)f2b(a0[j]);
        *(bf16x8*)&s_s4[n][0 + cg * 8] = o;
#pragma unroll
        for (int j = 0; j < 8; ++j) o[j] = (short)f2b(a1[j]);
        *(bf16x8*)&s_s4[n][128 + cg * 8] = o;
#pragma unroll
        for (int j = 0; j < 8; ++j) o[j] = (short)f2b(a2[j]);
        *(bf16x8*)&s_s4[n][256 + cg * 8] = o;
#pragma unroll
        for (int j = 0; j < 8; ++j) o[j] = (short)f2b(a3[j]);
        *(bf16x8*)&s_s4[n][384 + cg * 8] = o;
    }
    __syncthreads();

    int w = tid >> 6, l = tid & 63;
    int lr = l & 15, lk = (l >> 4) * 8, hi = l >> 4;

    // ---- phase 2: m = s4 @ wl (K=512). wave = 2 col-tiles ----
    {
        fx4 mq0 = {0,0,0,0}, mq1 = {0,0,0,0};
        int ct0 = w * 2, ct1 = w * 2 + 1;
#pragma unroll
        for (int ks = 0; ks < 16; ++ks) {
            int ko = ks * 32 + lk;
            bf16x8 aA = *(const bf16x8*)&s_s4[lr][ko];
            bf16x8 bA = *(const bf16x8*)&wl[(size_t)(ct0 * 16 + lr) * 512 + ko];
            bf16x8 bB = *(const bf16x8*)&wl[(size_t)(ct1 * 16 + lr) * 512 + ko];
            mq0 = __builtin_amdgcn_mfma_f32_16x16x32_bf16(aA, bA, mq0, 0, 0, 0);
            mq1 = __builtin_amdgcn_mfma_f32_16x16x32_bf16(aA, bB, mq1, 0, 0, 0);
        }
#pragma unroll
        for (int r = 0; r < 4; ++r) {
            m_bf[hi * 4 + r][ct0 * 16 + lr] = f2b(mq0[r]);
            m_bf[hi * 4 + r][ct1 * 16 + lr] = f2b(mq1[r]);
        }
    }
    __syncthreads();

    // ---- phase 3: GRU (mf from LDS, xf from xin, write xout) ----
    bf16x8 mf[4], xf[4];
#pragma unroll
    for (int ks = 0; ks < 4; ++ks) {
        mf[ks] = *(const bf16x8*)&m_bf[lr][ks * 32 + lk];
        xf[ks] = *(const bf16x8*)&xin[(size_t)(node0 + lr) * CC + ks * 32 + lk];
    }
#pragma unroll
    for (int cc = 0; cc < 2; ++cc) {
        int ct = w * 2 + cc;
        int row0 = ct * 16 + lr;
        fx4 ai[3], ah[3];
#pragma unroll
        for (int s = 0; s < 3; ++s) { ai[s] = (fx4){0,0,0,0}; ah[s] = (fx4){0,0,0,0}; }
#pragma unroll
        for (int ks = 0; ks < 4; ++ks) {
            int ko = ks * 32 + lk;
            bf16x8 bI[3], bH[3];
#pragma unroll
            for (int s = 0; s < 3; ++s) {
                bI[s] = *(const bf16x8*)&wgb[(size_t)(s * 128 + row0) * 128 + ko];
                bH[s] = *(const bf16x8*)&wgb[49152 + (size_t)(s * 128 + row0) * 128 + ko];
            }
#pragma unroll
            for (int s = 0; s < 3; ++s) {
                ai[s] = __builtin_amdgcn_mfma_f32_16x16x32_bf16(mf[ks], bI[s], ai[s], 0, 0, 0);
                ah[s] = __builtin_amdgcn_mfma_f32_16x16x32_bf16(xf[ks], bH[s], ah[s], 0, 0, 0);
            }
        }
        float bi0 = cvt[row0],        bh0 = cvt[384 + row0];
        float bi1 = cvt[128 + row0],  bh1 = cvt[512 + row0];
        float bi2 = cvt[256 + row0],  bh2 = cvt[640 + row0];
#pragma unroll
        for (int r = 0; r < 4; ++r) {
            int node = node0 + hi * 4 + r;
            float rg = sigm(ai[0][r] + bi0 + ah[0][r] + bh0);
            float zg = sigm(ai[1][r] + bi1 + ah[1][r] + bh1);
            float ny = ai[2][r] + bi2 + rg * (ah[2][r] + bh2);
            float ng = 2.f * sigm(2.f * ny) - 1.f;
            size_t xi = (size_t)node * CC + row0;
            float xo = b2f(xin[xi]);
            float xn = (1.f - zg) * ng + zg * xo;
            xout[xi] = f2b(xn);
            if (AGG) {
                int seg = batch[node] * TT + x_type[node];
                atomicAdd(&sums[(size_t)seg * CC + row0], xn);
                if (row0 == 0) atomicAdd(&cnta[seg], 1.0f);
            }
        }
    }
}

// ---------------- attnflat ----------------
__global__ __launch_bounds__(256) void attnflat_kernel(
    ushort* __restrict__ flatbf, const float* __restrict__ sums, const float* __restrict__ cnt,
    const float* __restrict__ cvt) {
    __shared__ float agg_s[TT][CC + 1];
    __shared__ float wpart[TT][8];
    __shared__ float attn_s[TT];
    int b = blockIdx.x, tid = threadIdx.x;
#pragma unroll
    for (int q = 0; q < 8; ++q) {
        int idx = tid + q * 256;
        int t = idx >> 7, c = idx & 127;
        float cv = cnt[b * TT + t];
        agg_s[t][c] = cv > 0.f ? sums[(size_t)(b * TT + t) * CC + c] / cv : 0.f;
    }
    __syncthreads();
    if (tid < 128) {
        int t = tid >> 3, p = tid & 7;
        float acc = 0.f;
        for (int i = 0; i < 16; ++i) acc += agg_s[t][p * 16 + i] * cvt[896 + p * 16 + i];
        wpart[t][p] = acc;
    }
    __syncthreads();
    if (tid < 16) {
        float acc = cvt[1034];
        for (int p = 0; p < 8; ++p) acc += wpart[tid][p];
        attn_s[tid] = acc;
    }
    __syncthreads();
    if (tid == 0) {
        float mx = attn_s[0];
        for (int t = 1; t < TT; ++t) mx = fmaxf(mx, attn_s[t]);
        float ssum = 0.f, ex[TT];
        for (int t = 0; t < TT; ++t) { ex[t] = __expf(attn_s[t] - mx); ssum += ex[t]; }
        for (int t = 0; t < TT; ++t) attn_s[t] = ex[t] / ssum;
    }
    __syncthreads();
#pragma unroll
    for (int q = 0; q < 8; ++q) {
        int idx = tid + q * 256;
        int t = idx >> 7, c = idx & 127;
        flatbf[(size_t)b * 2048 + idx] = f2b(agg_s[t][c] * attn_s[t]);
    }
}

// ---------------- enc MFMA ----------------
__global__ __launch_bounds__(256) void enc_mfma(
    float* __restrict__ encp, const ushort* __restrict__ flatbf, const ushort* __restrict__ wencT) {
    int tid = threadIdx.x;
    int w = tid >> 6, l = tid & 63;
    int bid = blockIdx.x;
    int m0 = (bid >> 2) * 16;
    int kc = (bid & 3) * 512;
    int lr = l & 15, lk = (l >> 4) * 8;
    fx4 acc0 = {0,0,0,0}, acc1 = {0,0,0,0};
    int ct0 = w * 2, ct1 = w * 2 + 1;
#pragma unroll
    for (int ks = 0; ks < 16; ++ks) {
        int ko = kc + ks * 32 + lk;
        bf16x8 af = *(const bf16x8*)&flatbf[(size_t)(m0 + lr) * 2048 + ko];
        bf16x8 b0 = *(const bf16x8*)&wencT[(size_t)(ct0 * 16 + lr) * 2048 + ko];
        bf16x8 b1 = *(const bf16x8*)&wencT[(size_t)(ct1 * 16 + lr) * 2048 + ko];
        acc0 = __builtin_amdgcn_mfma_f32_16x16x32_bf16(af, b0, acc0, 0, 0, 0);
        acc1 = __builtin_amdgcn_mfma_f32_16x16x32_bf16(af, b1, acc1, 0, 0, 0);
    }
#pragma unroll
    for (int r = 0; r < 4; ++r) {
        int row = m0 + (l >> 4) * 4 + r;
        encp[(size_t)(bid & 3) * BB * ENC + (size_t)row * ENC + ct0 * 16 + lr] = acc0[r];
        encp[(size_t)(bid & 3) * BB * ENC + (size_t)row * ENC + ct1 * 16 + lr] = acc1[r];
    }
}

// ---------------- dec ----------------
__global__ __launch_bounds__(256) void dec_kernel(
    void* __restrict__ out, const float* __restrict__ encp, const float* __restrict__ cvt,
    const int* __restrict__ flag) {
    const int isf = *flag;
    __shared__ float encs[ENC];
    int b = blockIdx.x, tid = threadIdx.x;
    if (tid < 128) {
        float e = cvt[768 + tid];
#pragma unroll
        for (int p = 0; p < 4; ++p) e += encp[(size_t)p * BB * ENC + (size_t)b * ENC + tid];
        encs[tid] = e;
    }
    __syncthreads();
    if (tid < NCLS) {
        float acc = cvt[1024 + tid];
        for (int j = 0; j < ENC; ++j) acc += encs[j] * cvt[1040 + j * NCLS + tid];
        int oi = b * NCLS + tid;
        if (isf) ((float*)out)[oi] = acc;
        else ((ushort*)out)[oi] = f2b(acc);
    }
}

extern "C" void kernel_launch(void* const* d_in, const int* in_sizes, int n_in,
                              void* d_out, int out_size, void* d_ws, size_t ws_size,
                              hipStream_t stream) {
    const int* x_type      = (const int*)d_in[0];
    const int* x_attrs     = (const int*)d_in[1];
    const int* x_mask      = (const int*)d_in[2];
    const int* edge_index  = (const int*)d_in[3];
    const int* edge_attr   = (const int*)d_in[4];
    const int* batch       = (const int*)d_in[6];
    const void* type_emb   = d_in[7];
    const void* attr_emb   = d_in[8];
    const void* W_msg      = d_in[9];
    const void* W_ih       = d_in[10];
    const void* W_hh       = d_in[11];
    const void* b_ih       = d_in[12];
    const void* b_hh       = d_in[13];
    const void* w_attn     = d_in[14];
    const void* b_attn     = d_in[15];
    const void* W_enc      = d_in[16];
    const void* b_enc      = d_in[17];
    const void* W_dec      = d_in[18];
    const void* b_dec      = d_in[19];

    char* p = (char*)d_ws;
    ushort* xbf0  = (ushort*)p;          p += (size_t)NN * CC * 2;       // 12.8 MB
    ushort* xbf1  = (ushort*)p;          p += (size_t)NN * CC * 2;       // 12.8 MB
    ushort* wstk  = (ushort*)p;          p += (size_t)LL * 128 * 512 * 2;// 0.5 MB
    ushort* wgb   = (ushort*)p;          p += (size_t)2 * 384 * 128 * 2;
    ushort* wencT = (ushort*)p;          p += (size_t)ENC * 2048 * 2;
    ushort* flatbf= (ushort*)p;          p += (size_t)BB * 2048 * 2;
    float*  encp  = (float*)p;           p += (size_t)4 * BB * ENC * 4;
    float*  cvt   = (float*)p;           p += 2320 * 4;
    float*  sums  = (float*)p;           p += (size_t)BB * TT * CC * 4;
    float*  cnta  = (float*)p;           p += (size_t)BB * TT * 4;
    uint*   csr   = (uint*)p;            p += (size_t)EE * 4;
    int*    cptr  = (int*)p;             p += (size_t)NN * 4;
    int*    btot  = (int*)p;             p += 256 * 4;
    int*    flag  = (int*)p;

    sniff_kernel<<<1, 1, 0, stream>>>(flag, W_enc);
    wstk_kernel<<<1024, 256, 0, stream>>>(wstk, W_msg, flag);
    wgru_kernel<<<384, 256, 0, stream>>>(wgb, W_ih, W_hh, flag);
    wencT_kernel<<<1024, 256, 0, stream>>>(wencT, W_enc, flag);
    bconv_kernel<<<10, 256, 0, stream>>>(cvt, b_ih, b_hh, b_enc, w_attn, b_dec, b_attn, W_dec, flag);
    embed_kernel<<<(NN * 64) / 256, 256, 0, stream>>>(xbf0, x_type, x_attrs, x_mask,
                                                      type_emb, attr_emb, flag);

    // ---- CSR build ----
    const int NB = (NN + 255) / 256;
    hipMemsetAsync(cptr, 0, (size_t)NN * sizeof(int), stream);
    deg_kernel<<<(EE + 255) / 256, 256, 0, stream>>>(cptr, edge_index);
    scan1_kernel<<<NB, 256, 0, stream>>>(cptr, btot);
    scan2_kernel<<<1, 256, 0, stream>>>(btot, NB);
    scan3_kernel<<<NB, 256, 0, stream>>>(cptr, btot);
    fill_kernel<<<(EE + 255) / 256, 256, 0, stream>>>(csr, cptr, edge_index, edge_attr);

    hipMemsetAsync(sums, 0, (size_t)(BB * TT * CC + BB * TT) * sizeof(float), stream);

    const int tile_grid = NN / 16;   // 3125 (exact)
    for (int l = 0; l < LL; ++l) {
        const ushort* xin = (l & 1) ? xbf1 : xbf0;
        ushort* xout      = (l & 1) ? xbf0 : xbf1;
        const ushort* wl = wstk + (size_t)l * 128 * 512;
        if (l < LL - 1)
            layer_fused<0><<<tile_grid, 256, 0, stream>>>(xin, xout, wl, wgb, cvt,
                                                          csr, cptr, sums, cnta, batch, x_type);
        else
            layer_fused<1><<<tile_grid, 256, 0, stream>>>(xin, xout, wl, wgb, cvt,
                                                          csr, cptr, sums, cnta, batch, x_type);
    }

    attnflat_kernel<<<BB, 256, 0, stream>>>(flatbf, sums, cnta, cvt);
    enc_mfma<<<64, 256, 0, stream>>>(encp, flatbf, wencT);
    dec_kernel<<<BB, 256, 0, stream>>>(d_out, encp, cvt, flag);
}

// Round 15
// 689.587 us; speedup vs baseline: 1.2209x; 1.2209x over previous
//
#include <hip/hip_runtime.h>
#include <hip/hip_bf16.h>

#define NN 50000
#define NP 50016   // padded node count (tile multiple)
#define EE 600000
#define AA 8
#define CC 128
#define TT 16
#define TE 4
#define LL 4
#define BB 256
#define ENC 128
#define NCLS 10
#define SROW 136   // m_bf LDS row stride in ushorts (272B)
#define STR 520    // s_tile LDS row stride in ushorts (1040B)

typedef __attribute__((ext_vector_type(8))) short bf16x8;
typedef __attribute__((ext_vector_type(4))) float fx4;

__device__ __forceinline__ float b2f(ushort u) {
    union { float f; uint32_t i; } v; v.i = ((uint32_t)u) << 16; return v.f;
}
__device__ __forceinline__ ushort f2b(float f) {
    union { float f; uint32_t i; } v; v.f = f;
    uint32_t x = v.i;
    x += 0x7FFFu + ((x >> 16) & 1u);
    return (ushort)(x >> 16);
}
__device__ __forceinline__ float ldw(const void* p, long i, int isf) {
    return isf ? ((const float*)p)[i] : b2f(((const ushort*)p)[i]);
}
__device__ __forceinline__ float sigm(float t) { return 1.f / (1.f + __expf(-t)); }

// bijective chunked XCD swizzle (m204): blocks with bid%8==k process a contiguous logical chunk
__device__ __forceinline__ int xcd_swz(int bid, int nwg) {
    int q = nwg >> 3, r = nwg & 7, x = bid & 7, o = bid >> 3;
    return (x < r ? x * (q + 1) : r * (q + 1) + (x - r) * q) + o;
}

// ---------------- dtype sniff ----------------
__global__ void sniff_kernel(int* flag, const void* W_enc_raw) {
    const ushort* u = (const ushort*)W_enc_raw;
    int good = 0;
    for (int i = 0; i < 256; ++i) {
        ushort v = u[i];
        int ex = (v >> 7) & 0xFF;
        if (v == 0 || (ex >= 100 && ex <= 126)) ++good;
    }
    *flag = (good >= 230) ? 0 : 1;   // 0 = bf16, 1 = f32
}

// ---------------- W_msg -> wstk[l][d][t*128+c]  (bf16, K=512 stacked) ----------------
__global__ __launch_bounds__(256) void wstk_kernel(ushort* __restrict__ wstk,
                                                   const void* __restrict__ W,
                                                   const int* __restrict__ flag) {
    const int isf = *flag;
    int idx = blockIdx.x * 256 + threadIdx.x;     // 0 .. 262143
    int l = idx >> 16;                             // layer 0..3
    int rem = idx & 65535;
    int d = rem >> 9, r2 = rem & 511;
    int t = r2 >> 7, c = r2 & 127;
    long src = ((long)(l * 4 + t) << 14) + c * 128 + d;   // W_msg[l][t][c][d]
    wstk[idx] = isf ? f2b(((const float*)W)[src]) : ((const ushort*)W)[src];
}

// ---------------- Wih||Whh -> bf16 ----------------
__global__ __launch_bounds__(256) void wgru_kernel(ushort* __restrict__ wgb,
                                                   const void* __restrict__ Wih,
                                                   const void* __restrict__ Whh,
                                                   const int* __restrict__ flag) {
    const int isf = *flag;
    int idx = blockIdx.x * 256 + threadIdx.x;
    if (idx >= 98304) return;
    int ih = (idx < 49152);
    int off = ih ? idx : idx - 49152;
    wgb[idx] = f2b(ldw(ih ? Wih : Whh, off, isf));
}

// ---------------- W_enc -> bf16 transposed [ENC][2048] ----------------
__global__ __launch_bounds__(256) void wencT_kernel(ushort* __restrict__ wencT,
                                                    const void* __restrict__ W_enc,
                                                    const int* __restrict__ flag) {
    const int isf = *flag;
    int idx = blockIdx.x * 256 + threadIdx.x;
    int j = idx >> 11, k = idx & 2047;
    wencT[idx] = f2b(ldw(W_enc, (long)k * ENC + j, isf));
}

// ---------------- small params -> f32 scratch ----------------
// 0 bih(384) | 384 bhh(384) | 768 b_enc(128) | 896 w_attn(128)
// 1024 b_dec(10) | 1034 b_attn(1) | 1040 W_dec(1280) | total 2320
__global__ __launch_bounds__(256) void bconv_kernel(float* __restrict__ cvt,
                                                    const void* __restrict__ bih, const void* __restrict__ bhh,
                                                    const void* __restrict__ b_enc, const void* __restrict__ w_attn,
                                                    const void* __restrict__ b_dec, const void* __restrict__ b_attn,
                                                    const void* __restrict__ W_dec,
                                                    const int* __restrict__ flag) {
    const int isf = *flag;
    int i = blockIdx.x * 256 + threadIdx.x;
    if (i < 384) cvt[i] = ldw(bih, i, isf);
    else if (i < 768) cvt[i] = ldw(bhh, i - 384, isf);
    else if (i < 896) cvt[i] = ldw(b_enc, i - 768, isf);
    else if (i < 1024) cvt[i] = ldw(w_attn, i - 896, isf);
    else if (i < 1034) cvt[i] = ldw(b_dec, i - 1024, isf);
    else if (i == 1034) cvt[i] = ldw(b_attn, 0, isf);
    else if (i >= 1040 && i < 2320) cvt[i] = ldw(W_dec, i - 1040, isf);
}

// ---------------- embed: bf16 state (pad rows zeroed) ----------------
__global__ __launch_bounds__(256) void embed_kernel(
    ushort* __restrict__ xbf,
    const int* __restrict__ x_type, const int* __restrict__ x_attrs,
    const int* __restrict__ x_mask, const void* __restrict__ type_emb,
    const void* __restrict__ attr_emb, const int* __restrict__ flag) {
    const int isf = *flag;
    int idx = blockIdx.x * 256 + threadIdx.x;
    int n = idx >> 6, c = idx & 63;
    if (n >= NP) return;
    if (n >= NN) { xbf[n * CC + c] = 0; xbf[n * CC + 64 + c] = 0; return; }
    int ty = x_type[n];
    xbf[n * CC + c] = f2b(ldw(type_emb, ty * 64 + c, isf));
    int cnt = x_mask[n];
    float s = 0.f;
    for (int a = 0; a < cnt; ++a) s += ldw(attr_emb, x_attrs[n * AA + a] * 64 + c, isf);
    xbf[n * CC + 64 + c] = f2b(s / (float)cnt);
}

// ---------------- CSR build ----------------
__global__ __launch_bounds__(256) void deg_kernel(int* __restrict__ cnt, const int* __restrict__ ei) {
    int e = blockIdx.x * 256 + threadIdx.x;
    if (e < EE) atomicAdd(&cnt[ei[EE + e]], 1);
}
__global__ __launch_bounds__(256) void scan1_kernel(int* __restrict__ cnt, int* __restrict__ btot) {
    __shared__ int s[256];
    int tid = threadIdx.x, i = blockIdx.x * 256 + tid;
    int v = (i < NN) ? cnt[i] : 0;
    s[tid] = v; __syncthreads();
    for (int off = 1; off < 256; off <<= 1) {
        int t = (tid >= off) ? s[tid - off] : 0; __syncthreads();
        s[tid] += t; __syncthreads();
    }
    if (i < NN) cnt[i] = s[tid] - v;
    if (tid == 255) btot[blockIdx.x] = s[255];
}
__global__ __launch_bounds__(256) void scan2_kernel(int* __restrict__ btot, int nb) {
    __shared__ int s[256];
    int tid = threadIdx.x;
    int v = (tid < nb) ? btot[tid] : 0;
    s[tid] = v; __syncthreads();
    for (int off = 1; off < 256; off <<= 1) {
        int t = (tid >= off) ? s[tid - off] : 0; __syncthreads();
        s[tid] += t; __syncthreads();
    }
    if (tid < nb) btot[tid] = s[tid] - v;
}
__global__ __launch_bounds__(256) void scan3_kernel(int* __restrict__ cnt, const int* __restrict__ btot) {
    int i = blockIdx.x * 256 + threadIdx.x;
    if (i < NN) cnt[i] += btot[blockIdx.x];
}
__global__ __launch_bounds__(256) void fill_kernel(uint* __restrict__ csr, int* __restrict__ cnt,
                                                   const int* __restrict__ ei, const int* __restrict__ ea) {
    int e = blockIdx.x * 256 + threadIdx.x;
    if (e >= EE) return;
    int d = ei[EE + e];
    int pos = atomicAdd(&cnt[d], 1);
    csr[pos] = (uint)ei[e] | ((uint)ea[e] << 16);
}

// ---------------- gather4: s4[d][t*128+c] = sum_{e:dst=d,type=t} xin[src][c]  (wave per node) ----------------
__global__ __launch_bounds__(256) void gather4_kernel(
    ushort* __restrict__ s4, const ushort* __restrict__ xin,
    const uint* __restrict__ csr, const int* __restrict__ endp) {
    int w = threadIdx.x >> 6, l = threadIdx.x & 63;
    int wg = xcd_swz(blockIdx.x, NN / 4);
    int node = wg * 4 + w;
    int start = (node == 0) ? 0 : endp[node - 1];
    int end = endp[node];
    int c0 = l * 2;
    float a0 = 0.f, b0 = 0.f, a1 = 0.f, b1 = 0.f;
    float a2 = 0.f, b2 = 0.f, a3 = 0.f, b3 = 0.f;
    int i = start;
    for (; i + 1 < end; i += 2) {
        uint pkA = csr[i], pkB = csr[i + 1];
        uint srcA = pkA & 0xFFFFu, tA = pkA >> 16;
        uint srcB = pkB & 0xFFFFu, tB = pkB >> 16;
        uint hvA = *(const uint*)&xin[((size_t)srcA << 7) + c0];
        uint hvB = *(const uint*)&xin[((size_t)srcB << 7) + c0];
        float loA = b2f((ushort)(hvA & 0xFFFFu)), hfA = b2f((ushort)(hvA >> 16));
        float loB = b2f((ushort)(hvB & 0xFFFFu)), hfB = b2f((ushort)(hvB >> 16));
        if (tA == 0)      { a0 += loA; b0 += hfA; }
        else if (tA == 1) { a1 += loA; b1 += hfA; }
        else if (tA == 2) { a2 += loA; b2 += hfA; }
        else              { a3 += loA; b3 += hfA; }
        if (tB == 0)      { a0 += loB; b0 += hfB; }
        else if (tB == 1) { a1 += loB; b1 += hfB; }
        else if (tB == 2) { a2 += loB; b2 += hfB; }
        else              { a3 += loB; b3 += hfB; }
    }
    if (i < end) {
        uint pk = csr[i];
        uint src = pk & 0xFFFFu, t = pk >> 16;
        uint hv = *(const uint*)&xin[((size_t)src << 7) + c0];
        float lo = b2f((ushort)(hv & 0xFFFFu)), hf = b2f((ushort)(hv >> 16));
        if (t == 0)      { a0 += lo; b0 += hf; }
        else if (t == 1) { a1 += lo; b1 += hf; }
        else if (t == 2) { a2 += lo; b2 += hf; }
        else             { a3 += lo; b3 += hf; }
    }
    size_t base = (size_t)node << 9;
    *(uint*)&s4[base +   0 + c0] = (uint)f2b(a0) | ((uint)f2b(b0) << 16);
    *(uint*)&s4[base + 128 + c0] = (uint)f2b(a1) | ((uint)f2b(b1) << 16);
    *(uint*)&s4[base + 256 + c0] = (uint)f2b(a2) | ((uint)f2b(b2) << 16);
    *(uint*)&s4[base + 384 + c0] = (uint)f2b(a3) | ((uint)f2b(b3) << 16);
}

// ---------------- msggru: LDS-staged s4 -> m = s4 @ wstk (K=512) -> GRU ----------------
template <int AGG>
__global__ __launch_bounds__(256) void msggru_kernel(
    const ushort* __restrict__ xin, ushort* __restrict__ xout,
    const ushort* __restrict__ s4, const ushort* __restrict__ wstk,
    const ushort* __restrict__ wgb, const float* __restrict__ cvt,
    float* __restrict__ sums, float* __restrict__ cnta,
    const int* __restrict__ batch, const int* __restrict__ x_type) {
    __shared__ ushort s_tile[32][STR];   // 32 rows x 512 data (+8 pad) = 32.5 KB
    __shared__ ushort m_bf[32][SROW];    // 8.7 KB
    int tid = threadIdx.x;
    int wg = xcd_swz(blockIdx.x, NP / 32);
    int node0 = wg * 32;

    // ---- stage s4 tile: 8 x contiguous 4KB cooperative loads ----
    {
        const ushort* src = &s4[(size_t)node0 << 9];
#pragma unroll
        for (int q = 0; q < 8; ++q) {
            int i8 = (q * 256 + tid) * 8;          // ushort index in 32x512 tile
            int n = i8 >> 9, c = i8 & 511;
            bf16x8 v = *(const bf16x8*)&src[i8];
            *(bf16x8*)&s_tile[n][c] = v;
        }
    }
    __syncthreads();

    int w = tid >> 6, l = tid & 63;
    int lr = l & 15, lk = (l >> 4) * 8, hi = l >> 4;

    // ---- phase A: message GEMM, K=512, A from LDS ----
    {
        fx4 mq[2][2];   // [cc][rt]
        mq[0][0] = (fx4){0,0,0,0}; mq[0][1] = (fx4){0,0,0,0};
        mq[1][0] = (fx4){0,0,0,0}; mq[1][1] = (fx4){0,0,0,0};
        int ct0 = w * 2, ct1 = w * 2 + 1;
#pragma unroll
        for (int ks = 0; ks < 16; ++ks) {
            int ko = ks * 32 + lk;
            bf16x8 aA = *(const bf16x8*)&s_tile[lr][ko];
            bf16x8 aB = *(const bf16x8*)&s_tile[16 + lr][ko];
            bf16x8 bA = *(const bf16x8*)&wstk[(size_t)(ct0 * 16 + lr) * 512 + ko];
            bf16x8 bB = *(const bf16x8*)&wstk[(size_t)(ct1 * 16 + lr) * 512 + ko];
            mq[0][0] = __builtin_amdgcn_mfma_f32_16x16x32_bf16(aA, bA, mq[0][0], 0, 0, 0);
            mq[0][1] = __builtin_amdgcn_mfma_f32_16x16x32_bf16(aB, bA, mq[0][1], 0, 0, 0);
            mq[1][0] = __builtin_amdgcn_mfma_f32_16x16x32_bf16(aA, bB, mq[1][0], 0, 0, 0);
            mq[1][1] = __builtin_amdgcn_mfma_f32_16x16x32_bf16(aB, bB, mq[1][1], 0, 0, 0);
        }
#pragma unroll
        for (int cc = 0; cc < 2; ++cc)
#pragma unroll
            for (int rt = 0; rt < 2; ++rt)
#pragma unroll
                for (int r = 0; r < 4; ++r)
                    m_bf[rt * 16 + hi * 4 + r][(w * 2 + cc) * 16 + lr] = f2b(mq[cc][rt][r]);
    }
    __syncthreads();

    // ---- phase B: GRU (mf from LDS, xf from xin, write xout) ----
    bf16x8 mf[2][4], xf[2][4];
#pragma unroll
    for (int rt = 0; rt < 2; ++rt)
#pragma unroll
        for (int ks = 0; ks < 4; ++ks) {
            mf[rt][ks] = *(const bf16x8*)&m_bf[rt * 16 + lr][ks * 32 + lk];
            xf[rt][ks] = *(const bf16x8*)&xin[(size_t)(node0 + rt * 16 + lr) * CC + ks * 32 + lk];
        }
#pragma unroll
    for (int cc = 0; cc < 2; ++cc) {
        int ct = w * 2 + cc;
        int row0 = ct * 16 + lr;
        fx4 ai[3][2], ah[3][2];
#pragma unroll
        for (int s = 0; s < 3; ++s)
#pragma unroll
            for (int rt = 0; rt < 2; ++rt) { ai[s][rt] = (fx4){0,0,0,0}; ah[s][rt] = (fx4){0,0,0,0}; }
#pragma unroll
        for (int ks = 0; ks < 4; ++ks) {
            int ko = ks * 32 + lk;
            bf16x8 bI[3], bH[3];
#pragma unroll
            for (int s = 0; s < 3; ++s) {
                bI[s] = *(const bf16x8*)&wgb[(size_t)(s * 128 + row0) * 128 + ko];
                bH[s] = *(const bf16x8*)&wgb[49152 + (size_t)(s * 128 + row0) * 128 + ko];
            }
#pragma unroll
            for (int s = 0; s < 3; ++s)
#pragma unroll
                for (int rt = 0; rt < 2; ++rt) {
                    ai[s][rt] = __builtin_amdgcn_mfma_f32_16x16x32_bf16(mf[rt][ks], bI[s], ai[s][rt], 0, 0, 0);
                    ah[s][rt] = __builtin_amdgcn_mfma_f32_16x16x32_bf16(xf[rt][ks], bH[s], ah[s][rt], 0, 0, 0);
                }
        }
        float bi0 = cvt[row0],        bh0 = cvt[384 + row0];
        float bi1 = cvt[128 + row0],  bh1 = cvt[512 + row0];
        float bi2 = cvt[256 + row0],  bh2 = cvt[640 + row0];
#pragma unroll
        for (int rt = 0; rt < 2; ++rt)
#pragma unroll
            for (int r = 0; r < 4; ++r) {
                int node = node0 + rt * 16 + hi * 4 + r;
                if (node >= NN) continue;
                float rg = sigm(ai[0][rt][r] + bi0 + ah[0][rt][r] + bh0);
                float zg = sigm(ai[1][rt][r] + bi1 + ah[1][rt][r] + bh1);
                float ny = ai[2][rt][r] + bi2 + rg * (ah[2][rt][r] + bh2);
                float ng = 2.f * sigm(2.f * ny) - 1.f;
                size_t xi = (size_t)node * CC + row0;
                float xo = b2f(xin[xi]);
                float xn = (1.f - zg) * ng + zg * xo;
                xout[xi] = f2b(xn);
                if (AGG) {
                    int seg = batch[node] * TT + x_type[node];
                    atomicAdd(&sums[(size_t)seg * CC + row0], xn);
                    if (row0 == 0) atomicAdd(&cnta[seg], 1.0f);
                }
            }
    }
}

// ---------------- attnflat ----------------
__global__ __launch_bounds__(256) void attnflat_kernel(
    ushort* __restrict__ flatbf, const float* __restrict__ sums, const float* __restrict__ cnt,
    const float* __restrict__ cvt) {
    __shared__ float agg_s[TT][CC + 1];
    __shared__ float wpart[TT][8];
    __shared__ float attn_s[TT];
    int b = blockIdx.x, tid = threadIdx.x;
#pragma unroll
    for (int q = 0; q < 8; ++q) {
        int idx = tid + q * 256;
        int t = idx >> 7, c = idx & 127;
        float cv = cnt[b * TT + t];
        agg_s[t][c] = cv > 0.f ? sums[(size_t)(b * TT + t) * CC + c] / cv : 0.f;
    }
    __syncthreads();
    if (tid < 128) {
        int t = tid >> 3, p = tid & 7;
        float acc = 0.f;
        for (int i = 0; i < 16; ++i) acc += agg_s[t][p * 16 + i] * cvt[896 + p * 16 + i];
        wpart[t][p] = acc;
    }
    __syncthreads();
    if (tid < 16) {
        float acc = cvt[1034];
        for (int p = 0; p < 8; ++p) acc += wpart[tid][p];
        attn_s[tid] = acc;
    }
    __syncthreads();
    if (tid == 0) {
        float mx = attn_s[0];
        for (int t = 1; t < TT; ++t) mx = fmaxf(mx, attn_s[t]);
        float ssum = 0.f, ex[TT];
        for (int t = 0; t < TT; ++t) { ex[t] = __expf(attn_s[t] - mx); ssum += ex[t]; }
        for (int t = 0; t < TT; ++t) attn_s[t] = ex[t] / ssum;
    }
    __syncthreads();
#pragma unroll
    for (int q = 0; q < 8; ++q) {
        int idx = tid + q * 256;
        int t = idx >> 7, c = idx & 127;
        flatbf[(size_t)b * 2048 + idx] = f2b(agg_s[t][c] * attn_s[t]);
    }
}

// ---------------- enc MFMA ----------------
__global__ __launch_bounds__(256) void enc_mfma(
    float* __restrict__ encp, const ushort* __restrict__ flatbf, const ushort* __restrict__ wencT) {
    int tid = threadIdx.x;
    int w = tid >> 6, l = tid & 63;
    int bid = blockIdx.x;
    int m0 = (bid >> 2) * 16;
    int kc = (bid & 3) * 512;
    int lr = l & 15, lk = (l >> 4) * 8;
    fx4 acc0 = {0,0,0,0}, acc1 = {0,0,0,0};
    int ct0 = w * 2, ct1 = w * 2 + 1;
#pragma unroll
    for (int ks = 0; ks < 16; ++ks) {
        int ko = kc + ks * 32 + lk;
        bf16x8 af = *(const bf16x8*)&flatbf[(size_t)(m0 + lr) * 2048 + ko];
        bf16x8 b0 = *(const bf16x8*)&wencT[(size_t)(ct0 * 16 + lr) * 2048 + ko];
        bf16x8 b1 = *(const bf16x8*)&wencT[(size_t)(ct1 * 16 + lr) * 2048 + ko];
        acc0 = __builtin_amdgcn_mfma_f32_16x16x32_bf16(af, b0, acc0, 0, 0, 0);
        acc1 = __builtin_amdgcn_mfma_f32_16x16x32_bf16(af, b1, acc1, 0, 0, 0);
    }
#pragma unroll
    for (int r = 0; r < 4; ++r) {
        int row = m0 + (l >> 4) * 4 + r;
        encp[(size_t)(bid & 3) * BB * ENC + (size_t)row * ENC + ct0 * 16 + lr] = acc0[r];
        encp[(size_t)(bid & 3) * BB * ENC + (size_t)row * ENC + ct1 * 16 + lr] = acc1[r];
    }
}

// ---------------- dec ----------------
__global__ __launch_bounds__(256) void dec_kernel(
    void* __restrict__ out, const float* __restrict__ encp, const float* __restrict__ cvt,
    const int* __restrict__ flag) {
    const int isf = *flag;
    __shared__ float encs[ENC];
    int b = blockIdx.x, tid = threadIdx.x;
    if (tid < 128) {
        float e = cvt[768 + tid];
#pragma unroll
        for (int p = 0; p < 4; ++p) e += encp[(size_t)p * BB * ENC + (size_t)b * ENC + tid];
        encs[tid] = e;
    }
    __syncthreads();
    if (tid < NCLS) {
        float acc = cvt[1024 + tid];
        for (int j = 0; j < ENC; ++j) acc += encs[j] * cvt[1040 + j * NCLS + tid];
        int oi = b * NCLS + tid;
        if (isf) ((float*)out)[oi] = acc;
        else ((ushort*)out)[oi] = f2b(acc);
    }
}

extern "C" void kernel_launch(void* const* d_in, const int* in_sizes, int n_in,
                              void* d_out, int out_size, void* d_ws, size_t ws_size,
                              hipStream_t stream) {
    const int* x_type      = (const int*)d_in[0];
    const int* x_attrs     = (const int*)d_in[1];
    const int* x_mask      = (const int*)d_in[2];
    const int* edge_index  = (const int*)d_in[3];
    const int* edge_attr   = (const int*)d_in[4];
    const int* batch       = (const int*)d_in[6];
    const void* type_emb   = d_in[7];
    const void* attr_emb   = d_in[8];
    const void* W_msg      = d_in[9];
    const void* W_ih       = d_in[10];
    const void* W_hh       = d_in[11];
    const void* b_ih       = d_in[12];
    const void* b_hh       = d_in[13];
    const void* w_attn     = d_in[14];
    const void* b_attn     = d_in[15];
    const void* W_enc      = d_in[16];
    const void* b_enc      = d_in[17];
    const void* W_dec      = d_in[18];
    const void* b_dec      = d_in[19];

    char* p = (char*)d_ws;
    ushort* xbf0  = (ushort*)p;          p += (size_t)NP * CC * 2;       // 12.8 MB
    ushort* xbf1  = (ushort*)p;          p += (size_t)NP * CC * 2;       // 12.8 MB
    ushort* s4    = (ushort*)p;          p += (size_t)NP * 512 * 2;      // 51.2 MB
    ushort* wstk  = (ushort*)p;          p += (size_t)LL * 128 * 512 * 2;// 0.5 MB
    ushort* wgb   = (ushort*)p;          p += (size_t)2 * 384 * 128 * 2;
    ushort* wencT = (ushort*)p;          p += (size_t)ENC * 2048 * 2;
    ushort* flatbf= (ushort*)p;          p += (size_t)BB * 2048 * 2;
    float*  encp  = (float*)p;           p += (size_t)4 * BB * ENC * 4;
    float*  cvt   = (float*)p;           p += 2320 * 4;
    float*  sums  = (float*)p;           p += (size_t)BB * TT * CC * 4;
    float*  cnta  = (float*)p;           p += (size_t)BB * TT * 4;
    uint*   csr   = (uint*)p;            p += (size_t)EE * 4;
    int*    cptr  = (int*)p;             p += (size_t)NN * 4;
    int*    btot  = (int*)p;             p += 256 * 4;
    int*    flag  = (int*)p;

    sniff_kernel<<<1, 1, 0, stream>>>(flag, W_enc);
    wstk_kernel<<<1024, 256, 0, stream>>>(wstk, W_msg, flag);
    wgru_kernel<<<384, 256, 0, stream>>>(wgb, W_ih, W_hh, flag);
    wencT_kernel<<<1024, 256, 0, stream>>>(wencT, W_enc, flag);
    bconv_kernel<<<10, 256, 0, stream>>>(cvt, b_ih, b_hh, b_enc, w_attn, b_dec, b_attn, W_dec, flag);
    embed_kernel<<<(NP * 64) / 256, 256, 0, stream>>>(xbf0, x_type, x_attrs, x_mask,
                                                      type_emb, attr_emb, flag);

    // ---- CSR build ----
    const int NB = (NN + 255) / 256;
    hipMemsetAsync(cptr, 0, (size_t)NN * sizeof(int), stream);
    deg_kernel<<<(EE + 255) / 256, 256, 0, stream>>>(cptr, edge_index);
    scan1_kernel<<<NB, 256, 0, stream>>>(cptr, btot);
    scan2_kernel<<<1, 256, 0, stream>>>(btot, NB);
    scan3_kernel<<<NB, 256, 0, stream>>>(cptr, btot);
    fill_kernel<<<(EE + 255) / 256, 256, 0, stream>>>(csr, cptr, edge_index, edge_attr);

    hipMemsetAsync(sums, 0, (size_t)(BB * TT * CC + BB * TT) * sizeof(float), stream);

    const int tile_grid = NP / 32;   // 1563
    for (int l = 0; l < LL; ++l) {
        const ushort* xin = (l & 1) ? xbf1 : xbf0;
        ushort* xout      = (l & 1) ? xbf0 : xbf1;
        gather4_kernel<<<NN / 4, 256, 0, stream>>>(s4, xin, csr, cptr);
        const ushort* wl = wstk + (size_t)l * 128 * 512;
        if (l < LL - 1)
            msggru_kernel<0><<<tile_grid, 256, 0, stream>>>(xin, xout, s4, wl, wgb, cvt,
                                                            sums, cnta, batch, x_type);
        else
            msggru_kernel<1><<<tile_grid, 256, 0, stream>>>(xin, xout, s4, wl, wgb, cvt,
                                                            sums, cnta, batch, x_type);
    }

    attnflat_kernel<<<BB, 256, 0, stream>>>(flatbf, sums, cnta, cvt);
    enc_mfma<<<64, 256, 0, stream>>>(encp, flatbf, wencT);
    dec_kernel<<<BB, 256, 0, stream>>>(d_out, encp, cvt, flag);
}